// Round 1
// baseline (1948.091 us; speedup 1.0000x reference)
//
#include <hip/hip_runtime.h>
#include <hip/hip_bf16.h>

// Problem constants
#define NB 256
#define TT 64
#define DD 1280
#define WW 256
#define HH 512
#define VV 10000

typedef short short8 __attribute__((ext_vector_type(8)));
typedef float f32x4 __attribute__((ext_vector_type(4)));

static __device__ __forceinline__ unsigned short f2bf(float x){
    unsigned int u = __float_as_uint(x);
    unsigned int r = u + 0x7FFFu + ((u >> 16) & 1u);   // RNE
    return (unsigned short)(r >> 16);
}

// ---------- prep: fp32 -> bf16 elementwise ----------
__global__ void k_conv(const float* __restrict__ in, unsigned short* __restrict__ out, int n){
    int i = blockIdx.x*blockDim.x + threadIdx.x;
    int stride = gridDim.x*blockDim.x;
    for (; i < n; i += stride) out[i] = f2bf(in[i]);
}

// ---------- prep: transpose + convert: in[R][C] f32 -> out[C][R] bf16 ----------
__global__ __launch_bounds__(256) void k_transpose_bf(const float* __restrict__ in,
                                                      unsigned short* __restrict__ out,
                                                      int R, int C){
    __shared__ unsigned short tile[64][17];
    int r0 = blockIdx.y*16, c0 = blockIdx.x*64;
    int tid = threadIdx.x;
    int c = tid & 63, rr = tid >> 6;
    #pragma unroll
    for (int j = 0; j < 4; ++j){
        int r = rr + j*4;
        unsigned short v = 0;
        if (r0 + r < R && c0 + c < C) v = f2bf(in[(size_t)(r0+r)*C + c0 + c]);
        tile[c][r] = v;
    }
    __syncthreads();
    int rw = tid & 15, cw = tid >> 4;
    #pragma unroll
    for (int j = 0; j < 4; ++j){
        int c2 = cw + j*16;
        if (c0 + c2 < C && r0 + rw < R)
            out[(size_t)(c0+c2)*R + r0 + rw] = tile[c2][rw];
    }
}

// ---------- h0 = features @ W_proj + b_proj (fp32) ----------
__global__ __launch_bounds__(512) void k_h0(const float* __restrict__ feat,
                                            const float* __restrict__ Wp,
                                            const float* __restrict__ bp,
                                            float* __restrict__ h0){
    int n0 = blockIdx.x*4;
    int h = threadIdx.x;
    float a0=0.f,a1=0.f,a2=0.f,a3=0.f;
    for (int d = 0; d < DD; ++d){
        float w = Wp[(size_t)d*HH + h];
        a0 += feat[(size_t)(n0+0)*DD + d]*w;
        a1 += feat[(size_t)(n0+1)*DD + d]*w;
        a2 += feat[(size_t)(n0+2)*DD + d]*w;
        a3 += feat[(size_t)(n0+3)*DD + d]*w;
    }
    float bb = bp[h];
    h0[(size_t)(n0+0)*HH+h] = a0+bb;
    h0[(size_t)(n0+1)*HH+h] = a1+bb;
    h0[(size_t)(n0+2)*HH+h] = a2+bb;
    h0[(size_t)(n0+3)*HH+h] = a3+bb;
}

// ---------- E2[v][h] = sum_w W_embed_bf[v][w] * Wx[w][h] + b[h]  (bf16 MFMA, fp32 out) ----------
__global__ __launch_bounds__(256) void k_e2(const unsigned short* __restrict__ Eb,
                                            const unsigned short* __restrict__ WxT,
                                            const float* __restrict__ bias,
                                            float* __restrict__ E2){
    int lane = threadIdx.x & 63;
    int wv   = threadIdx.x >> 6;           // 0..3
    int l15 = lane & 15, lhi = lane >> 4;
    int rbase = blockIdx.x*64 + wv*16;
    int arow = rbase + l15; if (arow > VV-1) arow = VV-1;
    short8 a[8];
    #pragma unroll
    for (int kk = 0; kk < 8; ++kk)
        a[kk] = *reinterpret_cast<const short8*>(Eb + (size_t)arow*WW + kk*32 + lhi*8);
    for (int ct = 0; ct < 32; ++ct){
        int c0 = ct*16;
        f32x4 acc = {0.f,0.f,0.f,0.f};
        #pragma unroll
        for (int kk = 0; kk < 8; ++kk){
            short8 b = *reinterpret_cast<const short8*>(WxT + (size_t)(c0 + l15)*WW + kk*32 + lhi*8);
            acc = __builtin_amdgcn_mfma_f32_16x16x32_bf16(a[kk], b, acc, 0, 0, 0);
        }
        float bb = bias[c0 + l15];
        #pragma unroll
        for (int r = 0; r < 4; ++r){
            int row = rbase + lhi*4 + r;
            if (row < VV) E2[(size_t)row*HH + c0 + l15] = acc[r] + bb;
        }
    }
}

// ---------- RNN: 16 samples per block, h in swizzled LDS, Wh^T streamed from L2 ----------
__global__ __launch_bounds__(512, 2) void k_rnn(const float* __restrict__ h0,
                                                const unsigned short* __restrict__ WhT,
                                                const float* __restrict__ E2,
                                                const int* __restrict__ caps,
                                                unsigned short* __restrict__ h_all){
    __shared__ unsigned short hl[16*512];   // XOR-swizzled [16][512] bf16
    int tid = threadIdx.x;
    int lane = tid & 63, wv = tid >> 6;     // 8 waves
    int l15 = lane & 15, lhi = lane >> 4;
    int n0 = blockIdx.x*16;
    // init from h0 (fp32 -> bf16)
    for (int i = tid; i < 16*512; i += 512){
        int r = i >> 9, c = i & 511;
        unsigned int byte = r*1024u + (((unsigned)c*2u) ^ ((unsigned)(r&7)<<4));
        hl[byte>>1] = f2bf(h0[(size_t)(n0+r)*HH + c]);
    }
    __syncthreads();
    int c0w = wv*64;
    for (int t = 0; t < TT; ++t){
        // A-fragments: row = l15, k = kk*32 + lhi*8 .. +7
        short8 a[16];
        int ar = l15;
        #pragma unroll
        for (int kk = 0; kk < 16; ++kk){
            unsigned int kb = ((unsigned)(kk*64 + lhi*16)) ^ ((unsigned)(ar&7)<<4);
            a[kk] = *reinterpret_cast<const short8*>(&hl[(ar*1024u + kb)>>1]);
        }
        int tok[4];
        #pragma unroll
        for (int r = 0; r < 4; ++r){
            int row = lhi*4 + r;
            tok[r] = caps[(n0+row)*(TT+1) + t];
        }
        __syncthreads();   // A-frags in regs; safe to overwrite hl below
        #pragma unroll
        for (int ct = 0; ct < 4; ++ct){
            int col = c0w + ct*16 + l15;
            f32x4 acc = {0.f,0.f,0.f,0.f};
            #pragma unroll
            for (int kk = 0; kk < 16; ++kk){
                short8 b = *reinterpret_cast<const short8*>(WhT + (size_t)col*HH + kk*32 + lhi*8);
                acc = __builtin_amdgcn_mfma_f32_16x16x32_bf16(a[kk], b, acc, 0, 0, 0);
            }
            #pragma unroll
            for (int r = 0; r < 4; ++r){
                int row = lhi*4 + r;
                float x = acc[r] + E2[(size_t)tok[r]*HH + col];
                float e = __expf(2.f*x);
                float th = 1.f - 2.f/(e + 1.f);       // tanh(x), saturates correctly
                unsigned short hb = f2bf(th);
                unsigned int byte = row*1024u + (((unsigned)col*2u) ^ ((unsigned)(row&7)<<4));
                hl[byte>>1] = hb;
                h_all[((size_t)(n0+row)*TT + t)*HH + col] = hb;
            }
        }
        __syncthreads();
    }
}

// ---------- scores GEMM + fused sum(exp) + target-score (no max needed: |score| < ~20) ----------
__global__ __launch_bounds__(512, 2) void k_scores(const unsigned short* __restrict__ hA,
                                                   const unsigned short* __restrict__ WoT,
                                                   const float* __restrict__ bo,
                                                   const int* __restrict__ caps,
                                                   float* __restrict__ part){
    int bid = blockIdx.x;
    int vhalf = bid & 1, rt = bid >> 1;      // vhalf clusters per XCD (bid%8 parity)
    int lane = threadIdx.x & 63, wv = threadIdx.x >> 6;   // 8 waves
    int l15 = lane & 15, lhi = lane >> 4;
    int r0 = rt*128 + wv*16;
    int arow = r0 + l15;
    short8 a[16];
    #pragma unroll
    for (int kk = 0; kk < 16; ++kk)
        a[kk] = *reinterpret_cast<const short8*>(hA + (size_t)arow*HH + kk*32 + lhi*8);
    int tg[4];
    float srun[4] = {0.f,0.f,0.f,0.f}, ts[4] = {0.f,0.f,0.f,0.f};
    #pragma unroll
    for (int r = 0; r < 4; ++r){
        int row = r0 + lhi*4 + r;
        int n = row >> 6, t = row & 63;
        tg[r] = caps[n*(TT+1) + t + 1];      // captions_out
    }
    int vt0 = vhalf ? 312 : 0, vt1 = vhalf ? 625 : 312;
    for (int vt = vt0; vt < vt1; ++vt){
        int vcol = vt*16 + l15;
        f32x4 acc = {0.f,0.f,0.f,0.f};
        #pragma unroll
        for (int kk = 0; kk < 16; ++kk){
            short8 b = *reinterpret_cast<const short8*>(WoT + (size_t)vcol*HH + kk*32 + lhi*8);
            acc = __builtin_amdgcn_mfma_f32_16x16x32_bf16(a[kk], b, acc, 0, 0, 0);
        }
        float bb = bo[vcol];
        #pragma unroll
        for (int r = 0; r < 4; ++r){
            float sc = acc[r] + bb;
            srun[r] += __expf(sc);
            if (tg[r] == vcol) ts[r] += sc;
        }
    }
    // reduce across the 16 column lanes
    #pragma unroll
    for (int off = 1; off < 16; off <<= 1){
        #pragma unroll
        for (int r = 0; r < 4; ++r){
            srun[r] += __shfl_xor(srun[r], off, 64);
            ts[r]   += __shfl_xor(ts[r],   off, 64);
        }
    }
    if (l15 == 0){
        #pragma unroll
        for (int r = 0; r < 4; ++r){
            int row = r0 + lhi*4 + r;
            part[((size_t)vhalf*(NB*TT) + row)*2 + 0] = srun[r];
            part[((size_t)vhalf*(NB*TT) + row)*2 + 1] = ts[r];
        }
    }
}

// ---------- final: nll = log(sum) - target_score, mask, sum/N ----------
__global__ __launch_bounds__(256) void k_loss(const float* __restrict__ part,
                                              const int* __restrict__ caps,
                                              float* __restrict__ out){
    __shared__ float red[256];
    int tid = threadIdx.x;
    float local = 0.f;
    for (int row = tid; row < NB*TT; row += 256){
        float s  = part[(size_t)row*2]     + part[((size_t)NB*TT + row)*2];
        float t0 = part[(size_t)row*2 + 1] + part[((size_t)NB*TT + row)*2 + 1];
        int n = row >> 6, t = row & 63;
        int tgt = caps[n*(TT+1) + t + 1];
        if (tgt != 0) local += __logf(s) - t0;
    }
    red[tid] = local;
    __syncthreads();
    for (int off = 128; off > 0; off >>= 1){
        if (tid < off) red[tid] += red[tid+off];
        __syncthreads();
    }
    if (tid == 0) out[0] = red[0] / (float)NB;
}

extern "C" void kernel_launch(void* const* d_in, const int* in_sizes, int n_in,
                              void* d_out, int out_size, void* d_ws, size_t ws_size,
                              hipStream_t stream) {
    const float* features = (const float*)d_in[0];
    const int*   captions = (const int*)  d_in[1];
    const float* W_proj   = (const float*)d_in[2];
    const float* b_proj   = (const float*)d_in[3];
    const float* W_embed  = (const float*)d_in[4];
    const float* Wx       = (const float*)d_in[5];
    const float* Wh       = (const float*)d_in[6];
    const float* b_       = (const float*)d_in[7];
    const float* W_out    = (const float*)d_in[8];
    const float* b_out    = (const float*)d_in[9];
    float* out = (float*)d_out;

    char* ws = (char*)d_ws;
    // byte offsets (all 256-aligned)
    float*          E2   = (float*)         (ws + 0);            // 10000*512*4 = 20,480,000
    float*          h0   = (float*)         (ws + 20480000);     // 256*512*4   =    524,288
    unsigned short* WhT  = (unsigned short*)(ws + 21004288);     // 512*512*2   =    524,288
    unsigned short* WxT  = (unsigned short*)(ws + 21528576);     // 512*256*2   =    262,144
    unsigned short* WoT  = (unsigned short*)(ws + 21790720);     // 10000*512*2 = 10,240,000
    unsigned short* Eb   = (unsigned short*)(ws + 32030720);     // 10000*256*2 =  5,120,000
    unsigned short* hA   = (unsigned short*)(ws + 37150720);     // 16384*512*2 = 16,777,216
    float*          part = (float*)         (ws + 53927936);     // 2*16384*2*4 =    262,144
    if (ws_size < 54190080u) return;  // visible as all-zero output

    k_conv<<<2048, 256, 0, stream>>>(W_embed, Eb, VV*WW);
    k_transpose_bf<<<dim3(8, 16),  256, 0, stream>>>(Wx,    WxT, WW, HH);
    k_transpose_bf<<<dim3(8, 32),  256, 0, stream>>>(Wh,    WhT, HH, HH);
    k_transpose_bf<<<dim3(157,32), 256, 0, stream>>>(W_out, WoT, HH, VV);
    k_h0<<<NB/4, 512, 0, stream>>>(features, W_proj, b_proj, h0);
    k_e2<<<157, 256, 0, stream>>>(Eb, WxT, b_, E2);
    k_rnn<<<NB/16, 512, 0, stream>>>(h0, WhT, E2, captions, hA);
    k_scores<<<256, 512, 0, stream>>>(hA, WoT, b_out, captions, part);
    k_loss<<<1, 256, 0, stream>>>(part, captions, out);
}

// Round 3
// 883.946 us; speedup vs baseline: 2.2039x; 2.2039x over previous
//
#include <hip/hip_runtime.h>
#include <hip/hip_bf16.h>

// Problem constants
#define NB 256
#define TT 64
#define DD 1280
#define WW 256
#define HH 512
#define VV 10000
#define VP 10112           // vocab padded to 79*128
#define NCT 79             // number of 128-col vocab tiles
#define MROWS (NB*TT)      // 16384 score rows

typedef short short8 __attribute__((ext_vector_type(8)));
typedef float f32x4 __attribute__((ext_vector_type(4)));

static __device__ __forceinline__ unsigned short f2bf(float x){
    unsigned int u = __float_as_uint(x);
    unsigned int r = u + 0x7FFFu + ((u >> 16) & 1u);   // RNE
    return (unsigned short)(r >> 16);
}
static __device__ __forceinline__ float bf2f(unsigned short u){
    return __uint_as_float(((unsigned int)u) << 16);
}
static __device__ __forceinline__ void gload16(const unsigned short* g, unsigned short* l){
    __builtin_amdgcn_global_load_lds(
        (const __attribute__((address_space(1))) void*)g,
        (__attribute__((address_space(3))) void*)l, 16, 0, 0);
}

// ---------- prep: transpose + convert: in[R][C] f32 -> out[Cp][R] bf16 (zero-pad C..Cp) ----------
__global__ __launch_bounds__(256) void k_transpose_bf(const float* __restrict__ in,
                                                      unsigned short* __restrict__ out,
                                                      int R, int C, int Cp){
    __shared__ unsigned short tile[64][17];
    int r0 = blockIdx.y*16, c0 = blockIdx.x*64;
    int tid = threadIdx.x;
    int c = tid & 63, rr = tid >> 6;
    #pragma unroll
    for (int j = 0; j < 4; ++j){
        int r = rr + j*4;
        unsigned short v = 0;
        if (r0 + r < R && c0 + c < C) v = f2bf(in[(size_t)(r0+r)*C + c0 + c]);
        tile[c][r] = v;
    }
    __syncthreads();
    int rw = tid & 15, cw = tid >> 4;
    #pragma unroll
    for (int j = 0; j < 4; ++j){
        int c2 = cw + j*16;
        if (c0 + c2 < Cp && r0 + rw < R)
            out[(size_t)(c0+c2)*R + r0 + rw] = tile[c2][rw];
    }
}

// ---------- bias pad: bop[i] = b_out[i] or -30000 ----------
__global__ __launch_bounds__(256) void k_biaspad(const float* __restrict__ bo, float* __restrict__ bop){
    int i = blockIdx.x*256 + threadIdx.x;
    if (i < VP) bop[i] = (i < VV) ? bo[i] : -30000.0f;
}

// ---------- h0 = features @ W_proj + b_proj (fp32) ----------
__global__ __launch_bounds__(512) void k_h0(const float* __restrict__ feat,
                                            const float* __restrict__ Wp,
                                            const float* __restrict__ bp,
                                            float* __restrict__ h0){
    int n0 = blockIdx.x*4;
    int h = threadIdx.x;
    float a0=0.f,a1=0.f,a2=0.f,a3=0.f;
    for (int d = 0; d < DD; ++d){
        float w = Wp[(size_t)d*HH + h];
        a0 += feat[(size_t)(n0+0)*DD + d]*w;
        a1 += feat[(size_t)(n0+1)*DD + d]*w;
        a2 += feat[(size_t)(n0+2)*DD + d]*w;
        a3 += feat[(size_t)(n0+3)*DD + d]*w;
    }
    float bb = bp[h];
    h0[(size_t)(n0+0)*HH+h] = a0+bb;
    h0[(size_t)(n0+1)*HH+h] = a1+bb;
    h0[(size_t)(n0+2)*HH+h] = a2+bb;
    h0[(size_t)(n0+3)*HH+h] = a3+bb;
}

// ---------- E2[v][h] = sum_w W_embed[v][w] * Wx[w][h] + b[h]  (bf16 MFMA, bf16 out) ----------
__global__ __launch_bounds__(256) void k_e2(const float* __restrict__ We,
                                            const unsigned short* __restrict__ WxT,
                                            const float* __restrict__ bias,
                                            unsigned short* __restrict__ E2b){
    int lane = threadIdx.x & 63;
    int wv   = threadIdx.x >> 6;           // 0..3
    int l15 = lane & 15, lhi = lane >> 4;
    int rbase = blockIdx.x*64 + wv*16;
    int arow = rbase + l15; if (arow > VV-1) arow = VV-1;
    short8 a[8];
    #pragma unroll
    for (int kk = 0; kk < 8; ++kk){
        const float* src = We + (size_t)arow*WW + kk*32 + lhi*8;
        float4 f0 = *reinterpret_cast<const float4*>(src);
        float4 f1 = *reinterpret_cast<const float4*>(src + 4);
        short8 v;
        v[0]=(short)f2bf(f0.x); v[1]=(short)f2bf(f0.y); v[2]=(short)f2bf(f0.z); v[3]=(short)f2bf(f0.w);
        v[4]=(short)f2bf(f1.x); v[5]=(short)f2bf(f1.y); v[6]=(short)f2bf(f1.z); v[7]=(short)f2bf(f1.w);
        a[kk] = v;
    }
    for (int ct = 0; ct < 32; ++ct){
        int c0 = ct*16;
        f32x4 acc = {0.f,0.f,0.f,0.f};
        #pragma unroll
        for (int kk = 0; kk < 8; ++kk){
            short8 b = *reinterpret_cast<const short8*>(WxT + (size_t)(c0 + l15)*WW + kk*32 + lhi*8);
            acc = __builtin_amdgcn_mfma_f32_16x16x32_bf16(a[kk], b, acc, 0, 0, 0);
        }
        float bb = bias[c0 + l15];
        #pragma unroll
        for (int r = 0; r < 4; ++r){
            int row = rbase + lhi*4 + r;
            if (row < VV) E2b[(size_t)row*HH + c0 + l15] = f2bf(acc[r] + bb);
        }
    }
}

// ---------- RNN: 16 samples per block, h in swizzled LDS, Wh^T streamed from L2 ----------
__global__ __launch_bounds__(512, 2) void k_rnn(const float* __restrict__ h0,
                                                const unsigned short* __restrict__ WhT,
                                                const unsigned short* __restrict__ E2b,
                                                const int* __restrict__ caps,
                                                unsigned short* __restrict__ h_all){
    __shared__ unsigned short hl[16*512];   // XOR-swizzled [16][512] bf16
    int tid = threadIdx.x;
    int lane = tid & 63, wv = tid >> 6;     // 8 waves
    int l15 = lane & 15, lhi = lane >> 4;
    int n0 = blockIdx.x*16;
    for (int i = tid; i < 16*512; i += 512){
        int r = i >> 9, c = i & 511;
        unsigned int byte = r*1024u + (((unsigned)c*2u) ^ ((unsigned)(r&7)<<4));
        hl[byte>>1] = f2bf(h0[(size_t)(n0+r)*HH + c]);
    }
    __syncthreads();
    int c0w = wv*64;
    for (int t = 0; t < TT; ++t){
        short8 a[16];
        int ar = l15;
        #pragma unroll
        for (int kk = 0; kk < 16; ++kk){
            unsigned int kb = ((unsigned)(kk*64 + lhi*16)) ^ ((unsigned)(ar&7)<<4);
            a[kk] = *reinterpret_cast<const short8*>(&hl[(ar*1024u + kb)>>1]);
        }
        int tok[4];
        #pragma unroll
        for (int r = 0; r < 4; ++r){
            int row = lhi*4 + r;
            tok[r] = caps[(n0+row)*(TT+1) + t];
        }
        __syncthreads();   // A-frags in regs; safe to overwrite hl below
        #pragma unroll
        for (int ct = 0; ct < 4; ++ct){
            int col = c0w + ct*16 + l15;
            f32x4 acc = {0.f,0.f,0.f,0.f};
            #pragma unroll
            for (int kk = 0; kk < 16; ++kk){
                short8 b = *reinterpret_cast<const short8*>(WhT + (size_t)col*HH + kk*32 + lhi*8);
                acc = __builtin_amdgcn_mfma_f32_16x16x32_bf16(a[kk], b, acc, 0, 0, 0);
            }
            #pragma unroll
            for (int r = 0; r < 4; ++r){
                int row = lhi*4 + r;
                float x = acc[r] + bf2f(E2b[(size_t)tok[r]*HH + col]);
                float e = __expf(2.f*x);
                float th = 1.f - 2.f/(e + 1.f);       // tanh(x)
                unsigned short hb = f2bf(th);
                unsigned int byte = row*1024u + (((unsigned)col*2u) ^ ((unsigned)(row&7)<<4));
                hl[byte>>1] = hb;
                h_all[((size_t)(n0+row)*TT + t)*HH + col] = hb;
            }
        }
        __syncthreads();
    }
}

// ---------- scores: tiled GEMM (m97 structure) + fused exp-sum + target gather ----------
// M=16384 x N=10112(pad) x K=512, 128x128 tile, BK=32, 4 waves (2x2), LDS-staged
// via global_load_lds with pre-swizzled sources.
// NOTE: waves (wr,0) and (wr,1) cover the SAME rows, different col halves ->
// partials must be cross-wc reduced (via LDS) before the single global write.
__global__ __launch_bounds__(256) void k_scores(const unsigned short* __restrict__ hA,
                                                const unsigned short* __restrict__ WoTp,
                                                const float* __restrict__ bop,
                                                const int* __restrict__ caps,
                                                float* __restrict__ pps,   // [NCT][MROWS]
                                                float* __restrict__ pts){  // [NCT][MROWS]
    __shared__ unsigned short As[128*32];
    __shared__ unsigned short Bs[128*32];
    // XCD-bijective swizzle: 10112 % 8 == 0
    int nwg = 128*NCT;
    int cpx = nwg >> 3;
    int bid = blockIdx.x;
    int logical = (bid & 7)*cpx + (bid >> 3);
    int ct = logical / 128, rt = logical % 128;     // rt fast within an XCD's chunk

    int tid = threadIdx.x;
    int lane = tid & 63, wv = tid >> 6;
    int l15 = lane & 15, lhi = lane >> 4;
    int wr = wv >> 1, wc = wv & 1;
    const size_t Abase = (size_t)rt*128*HH;
    const size_t Bbase = (size_t)ct*128*HH;

    // per-thread staging geometry (2 chunks each for A and B)
    unsigned srow[2], selem[2];
    #pragma unroll
    for (int i = 0; i < 2; ++i){
        unsigned row = (unsigned)((i*4 + wv)*16 + (lane >> 2));
        unsigned kc  = (unsigned)(lane & 3);
        srow[i]  = row;
        selem[i] = (kc ^ ((row >> 1) & 3u)) * 8u;   // element offset of 16B chunk in 32-elem row
    }

    f32x4 acc[4][4];
    #pragma unroll
    for (int m = 0; m < 4; ++m)
        #pragma unroll
        for (int n = 0; n < 4; ++n)
            acc[m][n] = (f32x4){0.f,0.f,0.f,0.f};

    for (int kt = 0; kt < 16; ++kt){
        #pragma unroll
        for (int i = 0; i < 2; ++i){
            gload16(hA   + Abase + (size_t)srow[i]*HH + kt*32 + selem[i], As + ((i*4 + wv) << 9));
            gload16(WoTp + Bbase + (size_t)srow[i]*HH + kt*32 + selem[i], Bs + ((i*4 + wv) << 9));
        }
        __syncthreads();   // drains vmcnt before barrier (compiler-enforced)
        short8 af[4], bf[4];
        #pragma unroll
        for (int m = 0; m < 4; ++m){
            unsigned row = (unsigned)(wr*64 + m*16 + l15);
            af[m] = *reinterpret_cast<const short8*>(As + row*32 + ((lhi ^ ((row>>1)&3))*8));
        }
        #pragma unroll
        for (int n = 0; n < 4; ++n){
            unsigned col = (unsigned)(wc*64 + n*16 + l15);
            bf[n] = *reinterpret_cast<const short8*>(Bs + col*32 + ((lhi ^ ((col>>1)&3))*8));
        }
        #pragma unroll
        for (int m = 0; m < 4; ++m)
            #pragma unroll
            for (int n = 0; n < 4; ++n)
                acc[m][n] = __builtin_amdgcn_mfma_f32_16x16x32_bf16(af[m], bf[n], acc[m][n], 0, 0, 0);
        __syncthreads();
    }

    // epilogue: bias + exp + target gather, reduce over 16 col-lanes
    int tg[4][4];
    float srun[4][4], ts[4][4];
    #pragma unroll
    for (int m = 0; m < 4; ++m)
        #pragma unroll
        for (int r = 0; r < 4; ++r){
            int gr = rt*128 + wr*64 + m*16 + lhi*4 + r;
            tg[m][r] = caps[(gr >> 6)*(TT+1) + (gr & 63) + 1];
            srun[m][r] = 0.f; ts[m][r] = 0.f;
        }
    #pragma unroll
    for (int n = 0; n < 4; ++n){
        int colg = ct*128 + wc*64 + n*16 + l15;
        float bb = bop[colg];
        #pragma unroll
        for (int m = 0; m < 4; ++m)
            #pragma unroll
            for (int r = 0; r < 4; ++r){
                float sc = acc[m][n][r] + bb;
                srun[m][r] += __expf(sc);
                if (tg[m][r] == colg) ts[m][r] += sc;
            }
    }
    #pragma unroll
    for (int off = 1; off < 16; off <<= 1)
        #pragma unroll
        for (int m = 0; m < 4; ++m)
            #pragma unroll
            for (int r = 0; r < 4; ++r){
                srun[m][r] += __shfl_xor(srun[m][r], off, 64);
                ts[m][r]   += __shfl_xor(ts[m][r],   off, 64);
            }
    // cross-wc reduction: waves (wr,0) and (wr,1) hold partials for the SAME rows.
    // Loop-final __syncthreads already drained all As reads -> safe to reuse as scratch.
    float* red = (float*)As;   // 256 floats
    if (wc == 1 && l15 == 0){
        #pragma unroll
        for (int m = 0; m < 4; ++m)
            #pragma unroll
            for (int r = 0; r < 4; ++r){
                int ri = wr*64 + m*16 + lhi*4 + r;
                red[ri]       = srun[m][r];
                red[128 + ri] = ts[m][r];
            }
    }
    __syncthreads();
    if (wc == 0 && l15 == 0){
        #pragma unroll
        for (int m = 0; m < 4; ++m)
            #pragma unroll
            for (int r = 0; r < 4; ++r){
                int ri = wr*64 + m*16 + lhi*4 + r;
                int gr = rt*128 + ri;
                pps[(size_t)ct*MROWS + gr] = srun[m][r] + red[ri];
                pts[(size_t)ct*MROWS + gr] = ts[m][r]   + red[128 + ri];
            }
    }
}

// ---------- loss stage 1: per-row nll, block partial sums (64 blocks x 256 thr) ----------
__global__ __launch_bounds__(256) void k_loss1(const float* __restrict__ pps,
                                               const float* __restrict__ pts,
                                               const int* __restrict__ caps,
                                               float* __restrict__ bsum){
    __shared__ float red[256];
    int tid = threadIdx.x;
    int row = blockIdx.x*256 + tid;
    float s = 0.f, t0 = 0.f;
    for (int ct = 0; ct < NCT; ++ct){
        s  += pps[(size_t)ct*MROWS + row];
        t0 += pts[(size_t)ct*MROWS + row];
    }
    int tgt = caps[(row >> 6)*(TT+1) + (row & 63) + 1];
    red[tid] = (tgt != 0) ? (__logf(s) - t0) : 0.f;
    __syncthreads();
    for (int off = 128; off > 0; off >>= 1){
        if (tid < off) red[tid] += red[tid+off];
        __syncthreads();
    }
    if (tid == 0) bsum[blockIdx.x] = red[0];
}

// ---------- loss stage 2: final sum / N ----------
__global__ __launch_bounds__(64) void k_loss2(const float* __restrict__ bsum, float* __restrict__ out){
    __shared__ float red[64];
    int tid = threadIdx.x;
    red[tid] = bsum[tid];
    __syncthreads();
    for (int off = 32; off > 0; off >>= 1){
        if (tid < off) red[tid] += red[tid+off];
        __syncthreads();
    }
    if (tid == 0) out[0] = red[0] / (float)NB;
}

extern "C" void kernel_launch(void* const* d_in, const int* in_sizes, int n_in,
                              void* d_out, int out_size, void* d_ws, size_t ws_size,
                              hipStream_t stream) {
    const float* features = (const float*)d_in[0];
    const int*   captions = (const int*)  d_in[1];
    const float* W_proj   = (const float*)d_in[2];
    const float* b_proj   = (const float*)d_in[3];
    const float* W_embed  = (const float*)d_in[4];
    const float* Wx       = (const float*)d_in[5];
    const float* Wh       = (const float*)d_in[6];
    const float* b_       = (const float*)d_in[7];
    const float* W_out    = (const float*)d_in[8];
    const float* b_out    = (const float*)d_in[9];
    float* out = (float*)d_out;

    char* ws = (char*)d_ws;
    // byte offsets (256-aligned)
    unsigned short* E2b  = (unsigned short*)(ws + 0);            // 10000*512*2 = 10,240,000
    float*          h0   = (float*)         (ws + 10240000);     // 256*512*4   =    524,288
    unsigned short* WhT  = (unsigned short*)(ws + 10764288);     // 512*512*2   =    524,288
    unsigned short* WxT  = (unsigned short*)(ws + 11288576);     // 512*256*2   =    262,144
    unsigned short* WoTp = (unsigned short*)(ws + 11550720);     // 10112*512*2 = 10,354,688
    float*          bop  = (float*)         (ws + 21905408);     // 10112*4     =     40,448
    unsigned short* hA   = (unsigned short*)(ws + 21945856);     // 16384*512*2 = 16,777,216
    float*          pps  = (float*)         (ws + 38723072);     // 79*16384*4  =  5,177,344
    float*          pts  = (float*)         (ws + 43900416);     // 79*16384*4  =  5,177,344
    float*          bsum = (float*)         (ws + 49077760);     // 64*4        =        256
    if (ws_size < 49078016u) return;

    k_transpose_bf<<<dim3(8, 16),  256, 0, stream>>>(Wx,    WxT,  WW, HH, HH);
    k_transpose_bf<<<dim3(8, 32),  256, 0, stream>>>(Wh,    WhT,  HH, HH, HH);
    k_transpose_bf<<<dim3(158,32), 256, 0, stream>>>(W_out, WoTp, HH, VV, VP);
    k_biaspad<<<40, 256, 0, stream>>>(b_out, bop);
    k_h0<<<NB/4, 512, 0, stream>>>(features, W_proj, b_proj, h0);
    k_e2<<<157, 256, 0, stream>>>(W_embed, WxT, b_, E2b);
    k_rnn<<<NB/16, 512, 0, stream>>>(h0, WhT, E2b, captions, hA);
    k_scores<<<128*NCT, 256, 0, stream>>>(hA, WoTp, bop, captions, pps, pts);
    k_loss1<<<64, 256, 0, stream>>>(pps, pts, captions, bsum);
    k_loss2<<<1, 64, 0, stream>>>(bsum, out);
}